// Round 3
// baseline (115.570 us; speedup 1.0000x reference)
//
#include <hip/hip_runtime.h>

// Problem constants (B, NBC, H, W, HID, OUT = 4, 128, 64, 64, 64, 1)
// ALL input tensors are float32 (reference uses jnp.float32 throughout).
#define BB   4
#define NBC  128
#define NINT 4096
#define HID  64

using half8   = __attribute__((ext_vector_type(8)))  _Float16; // MFMA f16 A/B frag (4 VGPRs)
using h2      = __attribute__((ext_vector_type(2)))  _Float16; // packed f16 pair (1 VGPR)
using float16 = __attribute__((ext_vector_type(16))) float;    // MFMA 32x32 acc
using f2      = __attribute__((ext_vector_type(2)))  float;
using int4v   = __attribute__((ext_vector_type(4)))  int;

static __device__ __forceinline__ h2 cvt_pkrtz(float a, float b) {
#if __has_builtin(__builtin_amdgcn_cvt_pkrtz)
    return __builtin_bit_cast(h2, __builtin_amdgcn_cvt_pkrtz(a, b));
#else
    h2 r;
    asm("v_cvt_pkrtz_f16_f32 %0, %1, %2" : "=v"(r) : "v"(a), "v"(b));
    return r;
#endif
}

// ---------------------------------------------------------------------------
// Kernel 1: boundary encoder + a' = relu(relu(x@W0+b0)@W1+b1) @ G0w[:64] + G0b
// EXACT round-0 form: f32 a' output (the f16-a' path is reverted while we
// isolate the f16 MFMA layout question).
// ---------------------------------------------------------------------------
__global__ void __launch_bounds__(256) bge_prep(
    const float* __restrict__ binfo,  // (4,128,3)
    const float* __restrict__ W0,     // (3,64)
    const float* __restrict__ b0,     // (64)
    const float* __restrict__ W1,     // (64,64)
    const float* __restrict__ b1,     // (64)
    const float* __restrict__ G0w,    // (66,64)
    const float* __restrict__ G0b,    // (64)
    float* __restrict__ aprime)       // (4,128,64) fp32
{
    __shared__ float sW1[HID * HID];   // 16 KB
    __shared__ float sG0[HID * HID];   // 16 KB
    __shared__ float shv [4][HID];
    __shared__ float shv2[4][HID];

    const int tid = threadIdx.x;
    const int wv  = tid >> 6;
    const int t   = tid & 63;
    const int row = blockIdx.x * 4 + wv;

    for (int idx = tid; idx < HID * HID / 4; idx += 256) {
        ((float4*)sW1)[idx] = ((const float4*)W1)[idx];
        ((float4*)sG0)[idx] = ((const float4*)G0w)[idx];
    }

    const float x0 = binfo[row*3+0];
    const float x1 = binfo[row*3+1];
    const float x2 = binfo[row*3+2];
    float h = fmaxf(x0*W0[t] + x1*W0[64+t] + x2*W0[128+t] + b0[t], 0.0f);
    shv[wv][t] = h;
    __syncthreads();                       // covers sW1/sG0 staging + shv

    float acc = b1[t];
    #pragma unroll 8
    for (int k = 0; k < HID; ++k) acc += shv[wv][k] * sW1[k*64 + t];
    shv2[wv][t] = fmaxf(acc, 0.0f);
    __syncthreads();

    float a = G0b[t];
    #pragma unroll 8
    for (int k = 0; k < HID; ++k) a += shv2[wv][k] * sG0[k*64 + t];
    aprime[row*HID + t] = a;
}

// ---------------------------------------------------------------------------
// Kernel 2: fused h1 build -> MFMA f16 -> f32 epilogue -> mean(bc)
// grid (128, 4): blockIdx.x = interior tile of 32, blockIdx.y = batch.
// 512 threads = 8 waves; wave w handles bc in [16w, 16w+16).
//
// DIAGNOSTIC ROUND: everything is the round-0 PASSING kernel (f32 a' in LDS,
// f32 h1 adds) EXCEPT:
//  * pack step = v_cvt_pkrtz_f16_f32 (2xf32 -> packed 2xf16) instead of
//    bf16-trunc perm (same instruction count, finer rounding);
//  * relu moved AFTER the pack as v_pk_max_f16 (relu(rtz(x)) == rtz(relu(x)));
//  * a+c adds done as f2 (v_pk_add_f32): per st 4 pk_add + 4 cvt + 4 pk_max
//    = 12 VALU vs round-0's 20;
//  * MFMA dtype = f16 with f16-RNE B-frags  <-- the hypothesis under test.
// If this fails at ~1e-2 like rounds 1-2, the f16 MFMA A/B fragment layout
// differs from bf16 and we revert to bf16 MFMA next round.
// MFMA 32x32x16: A[m=lane&31][k=hf*8+jj(+16*st)], B same k-mapping,
// C/D: col=lane&31, row=(reg&3)+8*(reg>>2)+4*hf  [verified for bf16].
// NOTE: no second __launch_bounds__ arg — R4 showed (512,4) caps VGPR at 64
// and spills acc/bfrag to scratch.
// ---------------------------------------------------------------------------
__global__ void __launch_bounds__(512) bge_main(
    const float* __restrict__ icoord, // (4,4096,2)
    const float* __restrict__ G0w,    // (66,64)  rows 64,65 used here
    const float* __restrict__ G1w,    // (64,64)
    const float* __restrict__ G1b,    // (64)
    const float* __restrict__ G2w,    // (64,1)
    const float* __restrict__ G2b,    // (1)
    const float* __restrict__ aprime, // (4,128,64) fp32
    float* __restrict__ out)          // (4,4096)
{
    // union: ldsA (8192 floats) reused as ldsS (8704) + red (512) after barrier
    __shared__ __align__(16) float smem[8704 + 512];   // 36 KB
    float* const ldsA = smem;
    float* const ldsS = smem;
    float* const red  = smem + 8704;

    const int b    = blockIdx.y;
    const int i0   = blockIdx.x * 32;
    const int tid  = threadIdx.x;
    const int wv   = tid >> 6;       // 0..7
    const int lane = tid & 63;
    const int hf   = lane >> 5;
    const int ln   = lane & 31;

    // stage a' (this batch, all 128 bc rows) into LDS, coalesced float4
    {
        const float4* src = (const float4*)(aprime + (size_t)b * NBC * HID);
        float4* dst = (float4*)ldsA;
        for (int idx = tid; idx < NBC*HID/4; idx += 512) dst[idx] = src[idx];
    }

    // per-lane c contribution as f2 pairs: cre2[st][j] covers k = st*16+hf*8+2j, +1
    const int i = i0 + ln;
    const float cx = icoord[((size_t)b*NINT + i)*2 + 0];
    const float cy = icoord[((size_t)b*NINT + i)*2 + 1];
    f2 cre2[4][4];
    #pragma unroll
    for (int st = 0; st < 4; ++st)
        #pragma unroll
        for (int j = 0; j < 4; ++j) {
            const int k = st*16 + hf*8 + 2*j;
            f2 t;
            t[0] = cx*G0w[64*64 + k]     + cy*G0w[65*64 + k];
            t[1] = cx*G0w[64*64 + k + 1] + cy*G0w[65*64 + k + 1];
            cre2[st][j] = t;
        }

    // B fragments of G1w (fp32 -> f16 RNE, once): k = st*16+hf*8+jj, n = t*32+ln
    half8 bfrag[4][2];
    #pragma unroll
    for (int st = 0; st < 4; ++st)
        #pragma unroll
        for (int t = 0; t < 2; ++t)
            #pragma unroll
            for (int jj = 0; jj < 8; ++jj) {
                const int k = st*16 + hf*8 + jj;
                bfrag[st][t][jj] = (_Float16)(G1w[k*64 + t*32 + ln]);
            }

    const float b1v0 = G1b[ln],  b1v1 = G1b[32 + ln];
    const float g2v0 = G2w[ln],  g2v1 = G2w[32 + ln];
    const float g2bv = G2b[0];

    h2 z2; z2[0] = (_Float16)0.0f; z2[1] = (_Float16)0.0f;
    const float16 zc = (float16)0.0f;     // C operand for st==0
    f2 s2[8];
    #pragma unroll
    for (int q = 0; q < 8; ++q) { s2[q][0] = 0.0f; s2[q][1] = 0.0f; }

    __syncthreads();  // ldsA ready

    #pragma unroll 2
    for (int bc = wv*16; bc < wv*16 + 16; ++bc) {
        const float* arow = ldsA + bc*HID;
        float16 acc0, acc1;
        #pragma unroll
        for (int st = 0; st < 4; ++st) {
            const float4* ap4 = (const float4*)(arow + st*16 + hf*8); // bcast/half
            const float4 v0 = ap4[0], v1 = ap4[1];
            f2 p0, p1, p2, p3;
            p0[0] = v0.x; p0[1] = v0.y;
            p1[0] = v0.z; p1[1] = v0.w;
            p2[0] = v1.x; p2[1] = v1.y;
            p3[0] = v1.z; p3[1] = v1.w;
            p0 += cre2[st][0];            // v_pk_add_f32
            p1 += cre2[st][1];
            p2 += cre2[st][2];
            p3 += cre2[st][3];
            h2 c0 = cvt_pkrtz(p0[0], p0[1]);   // 2xf32 -> packed 2xf16
            h2 c1 = cvt_pkrtz(p1[0], p1[1]);
            h2 c2 = cvt_pkrtz(p2[0], p2[1]);
            h2 c3 = cvt_pkrtz(p3[0], p3[1]);
#if __has_builtin(__builtin_elementwise_max)
            c0 = __builtin_elementwise_max(c0, z2);   // v_pk_max_f16 relu
            c1 = __builtin_elementwise_max(c1, z2);
            c2 = __builtin_elementwise_max(c2, z2);
            c3 = __builtin_elementwise_max(c3, z2);
#else
            c0[0] = c0[0] > z2[0] ? c0[0] : z2[0]; c0[1] = c0[1] > z2[1] ? c0[1] : z2[1];
            c1[0] = c1[0] > z2[0] ? c1[0] : z2[0]; c1[1] = c1[1] > z2[1] ? c1[1] : z2[1];
            c2[0] = c2[0] > z2[0] ? c2[0] : z2[0]; c2[1] = c2[1] > z2[1] ? c2[1] : z2[1];
            c3[0] = c3[0] > z2[0] ? c3[0] : z2[0]; c3[1] = c3[1] > z2[1] ? c3[1] : z2[1];
#endif
            int4v di;
            di[0] = __builtin_bit_cast(int, c0);
            di[1] = __builtin_bit_cast(int, c1);
            di[2] = __builtin_bit_cast(int, c2);
            di[3] = __builtin_bit_cast(int, c3);
            const half8 af = __builtin_bit_cast(half8, di);
            if (st == 0) {
                acc0 = __builtin_amdgcn_mfma_f32_32x32x16_f16(af, bfrag[0][0], zc, 0, 0, 0);
                acc1 = __builtin_amdgcn_mfma_f32_32x32x16_f16(af, bfrag[0][1], zc, 0, 0, 0);
            } else {
                acc0 = __builtin_amdgcn_mfma_f32_32x32x16_f16(af, bfrag[st][0], acc0, 0, 0, 0);
                acc1 = __builtin_amdgcn_mfma_f32_32x32x16_f16(af, bfrag[st][1], acc1, 0, 0, 0);
            }
        }
        // epilogue (round-0 structure, f2 adds): s += relu(h2 + G1b) . G2w
        #pragma unroll
        for (int q = 0; q < 8; ++q) {
            f2 a0; a0[0] = acc0[2*q]; a0[1] = acc0[2*q+1];
            f2 a1; a1[0] = acc1[2*q]; a1[1] = acc1[2*q+1];
            f2 bb0; bb0[0] = b1v0; bb0[1] = b1v0;
            f2 bb1; bb1[0] = b1v1; bb1[1] = b1v1;
            a0 += bb0;                    // v_pk_add_f32
            a1 += bb1;
            a0[0] = fmaxf(a0[0], 0.0f); a0[1] = fmaxf(a0[1], 0.0f);
            a1[0] = fmaxf(a1[0], 0.0f); a1[1] = fmaxf(a1[1], 0.0f);
            s2[q] += a0 * g2v0 + a1 * g2v1;
        }
    }

    __syncthreads();   // all waves done reading ldsA; reuse as ldsS

    {   // dump per-lane partials, stride 17 (odd -> conflict-free)
        float* base = ldsS + (wv*64 + lane)*17;
        #pragma unroll
        for (int q = 0; q < 8; ++q) { base[2*q] = s2[q][0]; base[2*q+1] = s2[q][1]; }
    }
    __syncthreads();

    // reduce over 8 waves x 32 lanes for each of 32 rows m
    // row m = (r&3) + 8*(r>>2) + 4*hf  ->  hf(m)=(m>>2)&1, r(m)=(m&3)|((m>>3)<<2)
    {
        const int m   = tid >> 4;        // 0..31
        const int ch  = tid & 15;        // 16 threads per row
        const int h_m = (m >> 2) & 1;
        const int r_m = (m & 3) | ((m >> 3) << 2);
        const int wvr = ch >> 1;         // 0..7
        const int ln0 = (ch & 1) * 16;
        float acc = 0.0f;
        #pragma unroll
        for (int q = 0; q < 16; ++q)
            acc += ldsS[(wvr*64 + h_m*32 + ln0 + q)*17 + r_m];
        red[m*16 + ch] = acc;
    }
    __syncthreads();

    if (tid < 32) {
        float tot = 0.0f;
        #pragma unroll
        for (int c2 = 0; c2 < 16; ++c2) tot += red[tid*16 + c2];
        out[(size_t)b*NINT + i0 + tid] = tot * (1.0f/128.0f) + g2bv;
    }
}

// ---------------------------------------------------------------------------
extern "C" void kernel_launch(void* const* d_in, const int* in_sizes, int n_in,
                              void* d_out, int out_size, void* d_ws, size_t ws_size,
                              hipStream_t stream) {
    const float* binfo  = (const float*)d_in[0];
    const float* icoord = (const float*)d_in[1];
    const float* W0     = (const float*)d_in[2];
    const float* b0     = (const float*)d_in[3];
    const float* W1     = (const float*)d_in[4];
    const float* b1     = (const float*)d_in[5];
    const float* G0w    = (const float*)d_in[6];
    const float* G0b    = (const float*)d_in[7];
    const float* G1w    = (const float*)d_in[8];
    const float* G1b    = (const float*)d_in[9];
    const float* G2w    = (const float*)d_in[10];
    const float* G2b    = (const float*)d_in[11];

    float* aprime = (float*)d_ws;   // 4*128*64 fp32 = 128 KB scratch

    hipLaunchKernelGGL(bge_prep, dim3(BB*NBC/4), dim3(256), 0, stream,
                       binfo, W0, b0, W1, b1, G0w, G0b, aprime);
    hipLaunchKernelGGL(bge_main, dim3(NINT/32, BB), dim3(512), 0, stream,
                       icoord, G0w, G1w, G1b, G2w, G2b, aprime,
                       (float*)d_out);
}

// Round 4
// 113.674 us; speedup vs baseline: 1.0167x; 1.0167x over previous
//
#include <hip/hip_runtime.h>

// Problem constants (B, NBC, H, W, HID, OUT = 4, 128, 64, 64, 64, 1)
// ALL input tensors are float32 (reference uses jnp.float32 throughout).
#define BB   4
#define NBC  128
#define NINT 4096
#define HID  64

using half8   = __attribute__((ext_vector_type(8)))  _Float16; // MFMA f16 A/B frag (4 VGPRs)
using h2      = __attribute__((ext_vector_type(2)))  _Float16; // packed f16 pair (1 VGPR)
using float16 = __attribute__((ext_vector_type(16))) float;    // MFMA 32x32 acc
using f2      = __attribute__((ext_vector_type(2)))  float;
using int4v   = __attribute__((ext_vector_type(4)))  int;

static __device__ __forceinline__ h2 cvt_pkrtz(float a, float b) {
#if __has_builtin(__builtin_amdgcn_cvt_pkrtz)
    return __builtin_bit_cast(h2, __builtin_amdgcn_cvt_pkrtz(a, b));
#else
    h2 r;
    asm("v_cvt_pkrtz_f16_f32 %0, %1, %2" : "=v"(r) : "v"(a), "v"(b));
    return r;
#endif
}

// ---------------------------------------------------------------------------
// Kernel 1: boundary encoder + a' = relu(relu(x@W0+b0)@W1+b1) @ G0w[:64] + G0b
// f32 a' output — PRECISION-CRITICAL: a' must reach the a'+c add in f32
// (f16 a' caused 1.05e-2 absmax via cancellation at relu boundaries, r1/r2).
// ---------------------------------------------------------------------------
__global__ void __launch_bounds__(256) bge_prep(
    const float* __restrict__ binfo,  // (4,128,3)
    const float* __restrict__ W0,     // (3,64)
    const float* __restrict__ b0,     // (64)
    const float* __restrict__ W1,     // (64,64)
    const float* __restrict__ b1,     // (64)
    const float* __restrict__ G0w,    // (66,64)
    const float* __restrict__ G0b,    // (64)
    float* __restrict__ aprime)       // (4,128,64) fp32
{
    __shared__ float sW1[HID * HID];   // 16 KB
    __shared__ float sG0[HID * HID];   // 16 KB
    __shared__ float shv [4][HID];
    __shared__ float shv2[4][HID];

    const int tid = threadIdx.x;
    const int wv  = tid >> 6;
    const int t   = tid & 63;
    const int row = blockIdx.x * 4 + wv;

    for (int idx = tid; idx < HID * HID / 4; idx += 256) {
        ((float4*)sW1)[idx] = ((const float4*)W1)[idx];
        ((float4*)sG0)[idx] = ((const float4*)G0w)[idx];
    }

    const float x0 = binfo[row*3+0];
    const float x1 = binfo[row*3+1];
    const float x2 = binfo[row*3+2];
    float h = fmaxf(x0*W0[t] + x1*W0[64+t] + x2*W0[128+t] + b0[t], 0.0f);
    shv[wv][t] = h;
    __syncthreads();                       // covers sW1/sG0 staging + shv

    float acc = b1[t];
    #pragma unroll 8
    for (int k = 0; k < HID; ++k) acc += shv[wv][k] * sW1[k*64 + t];
    shv2[wv][t] = fmaxf(acc, 0.0f);
    __syncthreads();

    float a = G0b[t];
    #pragma unroll 8
    for (int k = 0; k < HID; ++k) a += shv2[wv][k] * sG0[k*64 + t];
    aprime[row*HID + t] = a;
}

// ---------------------------------------------------------------------------
// Kernel 2: fused h1 build -> MFMA f16 (bias in C-operand) -> relu+dot2 -> mean
// grid (128, 4): blockIdx.x = interior tile of 32, blockIdx.y = batch.
// 512 threads = 8 waves; wave w handles bc in [16w, 16w+16).
//
// Round-4 changes (epilogue was ~80 VALU/bc, now ~48):
//  * G1b folded into the MFMA C-operand: st==0 uses C = splat(b1[n]) per acc
//    (n = lane -> uniform splat across the 16 acc regs). Exact f32 add, free.
//  * relu + g2-dot via packed f16: pair (acc0[r], acc1[r]) spans the two
//    n-halves (n=ln, n=32+ln) = the reduction dim. Per reg: cvt_pkrtz ->
//    v_pk_max_f16 -> v_dot2_f32_f16(hp, (g2[ln],g2[32+ln]), s[r]).
//    3 instr / 2 elems, f32 accumulation. rtz(relu(x)) == relu(rtz(x)).
//  * A-path unchanged from r3 (f32 a'+c add -> cvt_pkrtz -> pk_max -> MFMA).
// MFMA 32x32x16 f16: A[m=lane&31][k=hf*8+jj(+16*st)], B same k-mapping,
// C/D: col=lane&31 (= n dim), row=(reg&3)+8*(reg>>2)+4*hf (= i dim).
// ---------------------------------------------------------------------------
__global__ void __launch_bounds__(512) bge_main(
    const float* __restrict__ icoord, // (4,4096,2)
    const float* __restrict__ G0w,    // (66,64)  rows 64,65 used here
    const float* __restrict__ G1w,    // (64,64)
    const float* __restrict__ G1b,    // (64)
    const float* __restrict__ G2w,    // (64,1)
    const float* __restrict__ G2b,    // (1)
    const float* __restrict__ aprime, // (4,128,64) fp32
    float* __restrict__ out)          // (4,4096)
{
    // union: ldsA (8192 floats) reused as ldsS (8704) + red (512) after barrier
    __shared__ __align__(16) float smem[8704 + 512];   // 36 KB
    float* const ldsA = smem;
    float* const ldsS = smem;
    float* const red  = smem + 8704;

    const int b    = blockIdx.y;
    const int i0   = blockIdx.x * 32;
    const int tid  = threadIdx.x;
    const int wv   = tid >> 6;       // 0..7
    const int lane = tid & 63;
    const int hf   = lane >> 5;
    const int ln   = lane & 31;

    // stage a' (this batch, all 128 bc rows) into LDS, coalesced float4
    {
        const float4* src = (const float4*)(aprime + (size_t)b * NBC * HID);
        float4* dst = (float4*)ldsA;
        for (int idx = tid; idx < NBC*HID/4; idx += 512) dst[idx] = src[idx];
    }

    // per-lane c contribution as f2 pairs: cre2[st][j] covers k = st*16+hf*8+2j, +1
    const int i = i0 + ln;
    const float cx = icoord[((size_t)b*NINT + i)*2 + 0];
    const float cy = icoord[((size_t)b*NINT + i)*2 + 1];
    f2 cre2[4][4];
    #pragma unroll
    for (int st = 0; st < 4; ++st)
        #pragma unroll
        for (int j = 0; j < 4; ++j) {
            const int k = st*16 + hf*8 + 2*j;
            f2 t;
            t[0] = cx*G0w[64*64 + k]     + cy*G0w[65*64 + k];
            t[1] = cx*G0w[64*64 + k + 1] + cy*G0w[65*64 + k + 1];
            cre2[st][j] = t;
        }

    // B fragments of G1w (fp32 -> f16 RNE, once): k = st*16+hf*8+jj, n = t*32+ln
    half8 bfrag[4][2];
    #pragma unroll
    for (int st = 0; st < 4; ++st)
        #pragma unroll
        for (int t = 0; t < 2; ++t)
            #pragma unroll
            for (int jj = 0; jj < 8; ++jj) {
                const int k = st*16 + hf*8 + jj;
                bfrag[st][t][jj] = (_Float16)(G1w[k*64 + t*32 + ln]);
            }

    const float b1v0 = G1b[ln],  b1v1 = G1b[32 + ln];
    const float g2v0 = G2w[ln],  g2v1 = G2w[32 + ln];
    const float g2bv = G2b[0];

    // bias-in-C: C-operand splats (n = lane -> uniform over the 16 regs)
    float16 cb0, cb1;
    #pragma unroll
    for (int r = 0; r < 16; ++r) { cb0[r] = b1v0; cb1[r] = b1v1; }

    // packed g2 pair covering the two n-halves of this lane
    h2 g2pk; g2pk[0] = (_Float16)g2v0; g2pk[1] = (_Float16)g2v1;

    h2 z2; z2[0] = (_Float16)0.0f; z2[1] = (_Float16)0.0f;
    float s[16];
    #pragma unroll
    for (int r = 0; r < 16; ++r) s[r] = 0.0f;

    __syncthreads();  // ldsA ready

    #pragma unroll 2
    for (int bc = wv*16; bc < wv*16 + 16; ++bc) {
        const float* arow = ldsA + bc*HID;
        float16 acc0, acc1;
        #pragma unroll
        for (int st = 0; st < 4; ++st) {
            const float4* ap4 = (const float4*)(arow + st*16 + hf*8); // bcast/half
            const float4 v0 = ap4[0], v1 = ap4[1];
            f2 p0, p1, p2, p3;
            p0[0] = v0.x; p0[1] = v0.y;
            p1[0] = v0.z; p1[1] = v0.w;
            p2[0] = v1.x; p2[1] = v1.y;
            p3[0] = v1.z; p3[1] = v1.w;
            p0 += cre2[st][0];            // v_pk_add_f32 (MUST stay f32)
            p1 += cre2[st][1];
            p2 += cre2[st][2];
            p3 += cre2[st][3];
            h2 c0 = cvt_pkrtz(p0[0], p0[1]);   // 2xf32 -> packed 2xf16
            h2 c1 = cvt_pkrtz(p1[0], p1[1]);
            h2 c2 = cvt_pkrtz(p2[0], p2[1]);
            h2 c3 = cvt_pkrtz(p3[0], p3[1]);
#if __has_builtin(__builtin_elementwise_max)
            c0 = __builtin_elementwise_max(c0, z2);   // v_pk_max_f16 relu
            c1 = __builtin_elementwise_max(c1, z2);
            c2 = __builtin_elementwise_max(c2, z2);
            c3 = __builtin_elementwise_max(c3, z2);
#else
            c0[0] = c0[0] > z2[0] ? c0[0] : z2[0]; c0[1] = c0[1] > z2[1] ? c0[1] : z2[1];
            c1[0] = c1[0] > z2[0] ? c1[0] : z2[0]; c1[1] = c1[1] > z2[1] ? c1[1] : z2[1];
            c2[0] = c2[0] > z2[0] ? c2[0] : z2[0]; c2[1] = c2[1] > z2[1] ? c2[1] : z2[1];
            c3[0] = c3[0] > z2[0] ? c3[0] : z2[0]; c3[1] = c3[1] > z2[1] ? c3[1] : z2[1];
#endif
            int4v di;
            di[0] = __builtin_bit_cast(int, c0);
            di[1] = __builtin_bit_cast(int, c1);
            di[2] = __builtin_bit_cast(int, c2);
            di[3] = __builtin_bit_cast(int, c3);
            const half8 af = __builtin_bit_cast(half8, di);
            if (st == 0) {
                acc0 = __builtin_amdgcn_mfma_f32_32x32x16_f16(af, bfrag[0][0], cb0, 0, 0, 0);
                acc1 = __builtin_amdgcn_mfma_f32_32x32x16_f16(af, bfrag[0][1], cb1, 0, 0, 0);
            } else {
                acc0 = __builtin_amdgcn_mfma_f32_32x32x16_f16(af, bfrag[st][0], acc0, 0, 0, 0);
                acc1 = __builtin_amdgcn_mfma_f32_32x32x16_f16(af, bfrag[st][1], acc1, 0, 0, 0);
            }
        }
        // epilogue: s[r] += relu-dot over the two n-halves, packed f16 + dot2
        #pragma unroll
        for (int r = 0; r < 16; ++r) {
            h2 hp = cvt_pkrtz(acc0[r], acc1[r]);   // (h2+b1) pair -> f16 (rtz)
#if __has_builtin(__builtin_elementwise_max)
            hp = __builtin_elementwise_max(hp, z2);    // relu in f16
#else
            hp[0] = hp[0] > z2[0] ? hp[0] : z2[0]; hp[1] = hp[1] > z2[1] ? hp[1] : z2[1];
#endif
#if __has_builtin(__builtin_amdgcn_fdot2)
            s[r] = __builtin_amdgcn_fdot2(hp, g2pk, s[r], false);  // v_dot2_f32_f16
#else
            s[r] += (float)hp[0]*(float)g2pk[0] + (float)hp[1]*(float)g2pk[1];
#endif
        }
    }

    __syncthreads();   // all waves done reading ldsA; reuse as ldsS

    {   // dump per-lane partials, stride 17 (odd -> conflict-free)
        float* base = ldsS + (wv*64 + lane)*17;
        #pragma unroll
        for (int r = 0; r < 16; ++r) base[r] = s[r];
    }
    __syncthreads();

    // reduce over 8 waves x 32 lanes for each of 32 rows m
    // row m = (r&3) + 8*(r>>2) + 4*hf  ->  hf(m)=(m>>2)&1, r(m)=(m&3)|((m>>3)<<2)
    {
        const int m   = tid >> 4;        // 0..31
        const int ch  = tid & 15;        // 16 threads per row
        const int h_m = (m >> 2) & 1;
        const int r_m = (m & 3) | ((m >> 3) << 2);
        const int wvr = ch >> 1;         // 0..7
        const int ln0 = (ch & 1) * 16;
        float acc = 0.0f;
        #pragma unroll
        for (int q = 0; q < 16; ++q)
            acc += ldsS[(wvr*64 + h_m*32 + ln0 + q)*17 + r_m];
        red[m*16 + ch] = acc;
    }
    __syncthreads();

    if (tid < 32) {
        float tot = 0.0f;
        #pragma unroll
        for (int c2 = 0; c2 < 16; ++c2) tot += red[tid*16 + c2];
        out[(size_t)b*NINT + i0 + tid] = tot * (1.0f/128.0f) + g2bv;
    }
}

// ---------------------------------------------------------------------------
extern "C" void kernel_launch(void* const* d_in, const int* in_sizes, int n_in,
                              void* d_out, int out_size, void* d_ws, size_t ws_size,
                              hipStream_t stream) {
    const float* binfo  = (const float*)d_in[0];
    const float* icoord = (const float*)d_in[1];
    const float* W0     = (const float*)d_in[2];
    const float* b0     = (const float*)d_in[3];
    const float* W1     = (const float*)d_in[4];
    const float* b1     = (const float*)d_in[5];
    const float* G0w    = (const float*)d_in[6];
    const float* G0b    = (const float*)d_in[7];
    const float* G1w    = (const float*)d_in[8];
    const float* G1b    = (const float*)d_in[9];
    const float* G2w    = (const float*)d_in[10];
    const float* G2b    = (const float*)d_in[11];

    float* aprime = (float*)d_ws;   // 4*128*64 fp32 = 128 KB scratch

    hipLaunchKernelGGL(bge_prep, dim3(BB*NBC/4), dim3(256), 0, stream,
                       binfo, W0, b0, W1, b1, G0w, G0b, aprime);
    hipLaunchKernelGGL(bge_main, dim3(NINT/32, BB), dim3(512), 0, stream,
                       icoord, G0w, G1w, G1b, G2w, G2b, aprime,
                       (float*)d_out);
}